// Round 3
// baseline (630.707 us; speedup 1.0000x reference)
//
#include <hip/hip_runtime.h>

#define PRIOR_SCALE 0.3f
#define NEGF (-1e30f)
#define LOG2E_F 1.4426950408889634f
#define LN2_F 0.6931471805599453f
#define K_SS 16   // time steps per superstep (one barrier per K_SS steps)

__device__ __forceinline__ float fexp2(float x) { return __builtin_amdgcn_exp2f(x); }
__device__ __forceinline__ float flog2(float x) { return __builtin_amdgcn_logf(x); }

// base-2 logsumexp
__device__ __forceinline__ float lse2b(float a, float b) {
  float m = fmaxf(a, b);
  float d = fminf(a, b) - m;
  return m + flog2(1.0f + fexp2(d));
}
// 3-term: max term's exp2 is exactly 1 -> 2 exp + 1 log
__device__ __forceinline__ float lse3b(float a, float b, float c) {
  float mx = fmaxf(fmaxf(a, b), c);                      // v_max3
  float mn = fminf(fminf(a, b), c);                      // v_min3
  float md = fmaxf(fminf(a, b), fminf(fmaxf(a, b), c));  // v_med3
  return mx + flog2(1.0f + fexp2(md - mx) + fexp2(mn - mx));
}

// Blocks [0,N): CTC forward, 4 time-skewed waves (wave w runs superstep i in
// phase i+w; boundary alpha passed via once-written LDS mailbox mb[w][t]).
// Blocks [N, N+pblocks): label-prior partial sums on the otherwise-idle CUs.
extern "C" __global__ void __launch_bounds__(256)
ctc_fused_kernel(const float* __restrict__ lp, const float* __restrict__ lpri,
                 const int* __restrict__ tgt, const int* __restrict__ ilen,
                 const int* __restrict__ tlen, float* __restrict__ nll,
                 float* __restrict__ partial, int pblocks,
                 int T, int N, int V, int S) {
  if ((int)blockIdx.x >= N) {
    // ---------------- prior partial-sum path (no LDS, no barriers) --------
    const int pb = blockIdx.x - N;
    const int v = threadIdx.x;  // V == 256 == blockDim.x
    float s = 0.0f;
    for (int t = pb; t < T; t += pblocks) {
      const float* base = lp + (size_t)t * N * V + v;
      for (int nn = 0; nn < N; ++nn) {
        float x = base[(size_t)nn * V];
        s += (t < ilen[nn]) ? __expf(x) : 0.0f;
      }
    }
    partial[(size_t)pb * V + v] = s;
    return;
  }

  // ---------------- CTC forward path ------------------------------------
  const int n = blockIdx.x;
  const int g = threadIdx.x;   // owns positions 2g (blank), 2g+1 (label g)
  const int lane = g & 63;
  const int wid = g >> 6;
  __shared__ float mb[3][2048];   // mailbox: mb[w][t] = alpha(t)[128w+127]
  __shared__ float afin[513];

  const int len = __builtin_amdgcn_readfirstlane(ilen[n]);
  const int tl = tlen[n];

  const int* trow = tgt + n * S;
  const int tv = trow[g];
  const int tvp = (g > 0) ? trow[g - 1] : -1;
  const float sk = (g > 0 && tv != tvp) ? 0.0f : NEGF;
  const float ep1 = (-PRIOR_SCALE * lpri[tv]) * LOG2E_F;
  const float epb = (-PRIOR_SCALE * lpri[0]) * LOG2E_F;

  const size_t rstride = (size_t)N * V;
  const float* rp = lp + (size_t)n * V;   // blank column (v=0) of batch n
  const float* cp = rp + tv;              // this thread's label column

  // alpha init (t=0), base-2 domain
  float x0 = NEGF, x1 = NEGF, x2 = NEGF;
  {
    float b0 = rp[0], e0 = cp[0];
    if (g == 0) { x0 = fmaf(b0, LOG2E_F, epb); x1 = fmaf(e0, LOG2E_F, ep1); }
  }
  if (g < 3) mb[g][0] = NEGF;

  // emission register ring: slot k holds values for local step k of the
  // *next* superstep to execute (issued one full superstep ahead).
  float er[K_SS], br[K_SS];
#pragma unroll
  for (int k = 0; k < K_SS; ++k) {
    int t = 1 + k; if (t > len - 1) t = len - 1;
    er[k] = cp[(size_t)t * rstride];
    br[k] = rp[(size_t)t * rstride];
  }
  float mbreg = NEGF;  // boundary alpha for the NEXT step (slot t-1)

  asm volatile("s_waitcnt lgkmcnt(0)" ::: "memory");  // mb[*][0] visible
  __builtin_amdgcn_s_barrier();

  const int nss = (len - 1 + K_SS - 1) / K_SS;
  const int P = nss + 3;   // wave 3 lags 3 supersteps
  for (int p = 0; p < P; ++p) {
    const int i = p - wid;
    if (i >= 0 && i < nss) {
      const int t0 = 1 + i * K_SS;
#pragma unroll
      for (int k = 0; k < K_SS; ++k) {
        const int t = t0 + k;
        if (t < len) {   // wave-uniform
          float eb = fmaf(br[k], LOG2E_F, epb);
          float e1 = fmaf(er[k], LOG2E_F, ep1);
          // refill slot k for next superstep (consumed K_SS steps from now)
          int tn = t + K_SS; if (tn > len - 1) tn = len - 1;
          er[k] = cp[(size_t)tn * rstride];
          br[k] = rp[(size_t)tn * rstride];
          // mailbox prefetch for next step (slot t; written >=1 phase ago)
          float mbnext = (wid > 0) ? mb[wid - 1][t] : NEGF;
          float am1 = __shfl_up(x1, 1);
          if (lane == 0) am1 = mbreg;   // wid==0: stays NEGF
          float x1o = x1;
          float y0 = lse2b(x0, am1) + eb;
          float y1 = lse3b(x1, x0, am1 + sk) + e1;
          x0 = y0; x1 = y1;
          if (g == 255) x2 = lse2b(x2, x1o) + eb;   // position 512
          if (lane == 63 && wid < 3) mb[wid][t] = x1;
          mbreg = mbnext;
        }
      }
    }
    asm volatile("s_waitcnt lgkmcnt(0)" ::: "memory");  // mailbox writes visible
    __builtin_amdgcn_s_barrier();
  }

  afin[2 * g] = x0;
  afin[2 * g + 1] = x1;
  if (g == 255) afin[512] = x2;
  __syncthreads();
  if (g == 0) {
    const int i1 = 2 * tl;
    float ll = lse2b(afin[i1], afin[i1 - 1]) * LN2_F;
    nll[n] = -ll / (float)tl;
  }
}

extern "C" __global__ void finalize_kernel(const float* __restrict__ partial, int pblocks,
                                           const float* __restrict__ nll,
                                           float* __restrict__ out, int N, int V) {
  const int v = threadIdx.x;  // 256 == V
  float s = 0.0f;
  for (int pb = 0; pb < pblocks; ++pb) s += partial[(size_t)pb * V + v];
  out[1 + v] = __logf(s);
  if (v == 0) {
    float acc = 0.0f;
#pragma unroll 8
    for (int i = 0; i < N; ++i) acc += nll[i];
    out[0] = acc / (float)N;
  }
}

extern "C" void kernel_launch(void* const* d_in, const int* in_sizes, int n_in,
                              void* d_out, int out_size, void* d_ws, size_t ws_size,
                              hipStream_t stream) {
  const float* lp   = (const float*)d_in[0];  // [T,N,V] fp32
  const float* lpri = (const float*)d_in[1];  // [1,V]   fp32
  const int*   tgt  = (const int*)d_in[2];    // [N,S]
  const int*   ilen = (const int*)d_in[3];    // [N]
  const int*   tlen = (const int*)d_in[4];    // [N]
  const int V = in_sizes[1];
  const int N = in_sizes[3];
  const int S = in_sizes[2] / N;
  const int T = in_sizes[0] / (N * V);

  int pblocks = 200;  // 32 + 200 = 232 blocks, all co-resident
  size_t need = ((size_t)pblocks * V + 64) * sizeof(float);
  if (ws_size < need) {
    long avail = (long)(ws_size / sizeof(float)) - 64;
    pblocks = (int)(avail / V);
    if (pblocks < 1) pblocks = 1;
  }

  float* out = (float*)d_out;                   // [0]=loss, [1..V]=prior logsumexp
  float* partial = (float*)d_ws;                // [pblocks*V]
  float* nll = partial + (size_t)pblocks * V;   // [N]

  ctc_fused_kernel<<<N + pblocks, 256, 0, stream>>>(lp, lpri, tgt, ilen, tlen,
                                                    nll, partial, pblocks, T, N, V, S);
  finalize_kernel<<<1, 256, 0, stream>>>(partial, pblocks, nll, out, N, V);
}

// Round 4
// 533.507 us; speedup vs baseline: 1.1822x; 1.1822x over previous
//
#include <hip/hip_runtime.h>

#define PRIOR_SCALE 0.3f
#define NEGF (-1e30f)
#define LOG2E_F 1.4426950408889634f
#define LN2_F 0.6931471805599453f
#define K_SS 16   // time steps per superstep (one barrier per K_SS steps)

__device__ __forceinline__ float fexp2(float x) { return __builtin_amdgcn_exp2f(x); }
__device__ __forceinline__ float flog2(float x) { return __builtin_amdgcn_logf(x); }

// base-2 logsumexp
__device__ __forceinline__ float lse2b(float a, float b) {
  float m = fmaxf(a, b);
  float d = fminf(a, b) - m;
  return m + flog2(1.0f + fexp2(d));
}
// 3-term: max term's exp2 is exactly 1 -> 2 exp + 1 log
__device__ __forceinline__ float lse3b(float a, float b, float c) {
  float mx = fmaxf(fmaxf(a, b), c);                      // v_max3
  float mn = fminf(fminf(a, b), c);                      // v_min3
  float md = fmaxf(fminf(a, b), fminf(fmaxf(a, b), c));  // v_med3
  return mx + flog2(1.0f + fexp2(md - mx) + fexp2(mn - mx));
}

// lane-1 -> lane shift via DPP wave_shr:1 (pure VALU, no LDS pipe).
// Lane 0 receives `fill` (the invalid-lane rule returns `old` when bound_ctrl=0).
__device__ __forceinline__ float shr1_dpp(float x, float fill) {
  return __int_as_float(__builtin_amdgcn_update_dpp(
      __float_as_int(fill), __float_as_int(x), 0x138 /*wave_shr:1*/, 0xF, 0xF, false));
}

// Blocks [0,N): CTC forward, 4 time-skewed waves (wave w runs superstep i in
// phase p=i+w; boundary alpha passes through once-written LDS mailbox mb[w][t],
// bulk-read per superstep). Blocks [N,N+pblocks): label-prior partial sums.
extern "C" __global__ void __launch_bounds__(256)
ctc_fused_kernel(const float* __restrict__ lp, const float* __restrict__ lpri,
                 const int* __restrict__ tgt, const int* __restrict__ ilen,
                 const int* __restrict__ tlen, float* __restrict__ nll,
                 float* __restrict__ partial, int pblocks,
                 int T, int N, int V, int S) {
  if ((int)blockIdx.x >= N) {
    const int pb = blockIdx.x - N;
    const int v = threadIdx.x;  // V == 256 == blockDim.x
    float s = 0.0f;
    for (int t = pb; t < T; t += pblocks) {
      const float* base = lp + (size_t)t * N * V + v;
      for (int nn = 0; nn < N; ++nn) {
        float x = base[(size_t)nn * V];
        s += (t < ilen[nn]) ? __expf(x) : 0.0f;
      }
    }
    partial[(size_t)pb * V + v] = s;
    return;
  }

  // ---------------- CTC forward path ------------------------------------
  const int n = blockIdx.x;
  const int g = threadIdx.x;   // owns positions 2g (blank), 2g+1 (label g)
  const int lane = g & 63;
  const int wid = __builtin_amdgcn_readfirstlane(threadIdx.x >> 6);  // uniform->SGPR
  __shared__ __align__(16) float mb[3][2048];  // mb[w][t] = alpha(t)[128w+127]
  __shared__ float afin[513];

  const int len = __builtin_amdgcn_readfirstlane(ilen[n]);
  const int tl = tlen[n];

  const int* trow = tgt + n * S;
  const int tv = trow[g];
  const int tvp = (g > 0) ? trow[g - 1] : -1;
  const float sk = (g > 0 && tv != tvp) ? 0.0f : NEGF;
  const float ep1 = (-PRIOR_SCALE * lpri[tv]) * LOG2E_F;
  const float epb = (-PRIOR_SCALE * lpri[0]) * LOG2E_F;

  const size_t rstride = (size_t)N * V;
  const float* rp = lp + (size_t)n * V;   // column 0 (blank) of batch n

  // alpha init (t=0), base-2 domain
  float x0 = NEGF, x1 = NEGF, x2 = NEGF;
  {
    float b0 = rp[0], e0 = rp[tv];
    if (g == 0) { x0 = fmaf(b0, LOG2E_F, epb); x1 = fmaf(e0, LOG2E_F, ep1); }
  }
  if (g < 3) mb[g][0] = NEGF;

  // ---- emission ring: 16 named (e,b) pairs; slot k feeds local step k ----
  float eR0, eR1, eR2, eR3, eR4, eR5, eR6, eR7,
        eR8, eR9, eR10, eR11, eR12, eR13, eR14, eR15;
  float bR0, bR1, bR2, bR3, bR4, bR5, bR6, bR7,
        bR8, bR9, bR10, bR11, bR12, bR13, bR14, bR15;
  {
    const float* ip = rp + rstride;  // row 1
#define INIT_SLOT(K) { eR##K = ip[tv]; bR##K = ip[0]; ip += rstride; }
    INIT_SLOT(0) INIT_SLOT(1) INIT_SLOT(2) INIT_SLOT(3)
    INIT_SLOT(4) INIT_SLOT(5) INIT_SLOT(6) INIT_SLOT(7)
    INIT_SLOT(8) INIT_SLOT(9) INIT_SLOT(10) INIT_SLOT(11)
    INIT_SLOT(12) INIT_SLOT(13) INIT_SLOT(14) INIT_SLOT(15)
#undef INIT_SLOT
  }
  const float* rowp = rp + (size_t)(1 + K_SS) * rstride;  // next refill row (t=1 -> row 17)

  float mv0, mv1, mv2, mv3, mv4, mv5, mv6, mv7,
        mv8, mv9, mv10, mv11, mv12, mv13, mv14, mv15;

  asm volatile("s_waitcnt lgkmcnt(0)" ::: "memory");  // mb[*][0] visible
  __builtin_amdgcn_s_barrier();

  const int nss = (len - 1 + K_SS - 1) / K_SS;
  const int P = nss + 3;

#define STEP(KK, T_) {                                                         \
    const int t = (T_);                                                        \
    if (t < len) {                                                             \
      float eb = fmaf(bR##KK, LOG2E_F, epb);                                   \
      float e1 = fmaf(eR##KK, LOG2E_F, ep1);                                   \
      eR##KK = rowp[tv];                                                       \
      bR##KK = rowp[0];                                                        \
      rowp += ((t + 1 + K_SS) < len) ? rstride : 0;                            \
      float am1 = shr1_dpp(x1, mv##KK);                                        \
      float x1o = x1;                                                          \
      float y0 = lse2b(x0, am1) + eb;                                          \
      float y1 = lse3b(x1, x0, am1 + sk) + e1;                                 \
      x0 = y0; x1 = y1;                                                        \
      if (g == 255) x2 = lse2b(x2, x1o) + eb;                                  \
      if (lane == 63 && wid < 3) mb[wid][t] = x1;                              \
    } }

  for (int p = 0; p < P; ++p) {
    const int i = p - wid;
    if (i >= 0 && i < nss) {
      const int t0 = 1 + i * K_SS;
      if (wid > 0) {
        // bulk mailbox read: mb[wid-1][t0-1 .. t0+14] (all >=1 phase old)
        const float4* mrow = (const float4*)&mb[wid - 1][t0 - 1];  // 64B aligned
        float4 q0 = mrow[0], q1 = mrow[1], q2 = mrow[2], q3 = mrow[3];
        mv0 = q0.x; mv1 = q0.y; mv2 = q0.z; mv3 = q0.w;
        mv4 = q1.x; mv5 = q1.y; mv6 = q1.z; mv7 = q1.w;
        mv8 = q2.x; mv9 = q2.y; mv10 = q2.z; mv11 = q2.w;
        mv12 = q3.x; mv13 = q3.y; mv14 = q3.z; mv15 = q3.w;
      } else {
        mv0 = mv1 = mv2 = mv3 = mv4 = mv5 = mv6 = mv7 = NEGF;
        mv8 = mv9 = mv10 = mv11 = mv12 = mv13 = mv14 = mv15 = NEGF;
      }
      STEP(0, t0 + 0)  STEP(1, t0 + 1)  STEP(2, t0 + 2)  STEP(3, t0 + 3)
      STEP(4, t0 + 4)  STEP(5, t0 + 5)  STEP(6, t0 + 6)  STEP(7, t0 + 7)
      STEP(8, t0 + 8)  STEP(9, t0 + 9)  STEP(10, t0 + 10) STEP(11, t0 + 11)
      STEP(12, t0 + 12) STEP(13, t0 + 13) STEP(14, t0 + 14) STEP(15, t0 + 15)
    }
    asm volatile("s_waitcnt lgkmcnt(0)" ::: "memory");  // mailbox writes visible
    __builtin_amdgcn_s_barrier();
  }
#undef STEP

  afin[2 * g] = x0;
  afin[2 * g + 1] = x1;
  if (g == 255) afin[512] = x2;
  __syncthreads();
  if (g == 0) {
    const int i1 = 2 * tl;
    float ll = lse2b(afin[i1], afin[i1 - 1]) * LN2_F;
    nll[n] = -ll / (float)tl;
  }
}

extern "C" __global__ void finalize_kernel(const float* __restrict__ partial, int pblocks,
                                           const float* __restrict__ nll,
                                           float* __restrict__ out, int N, int V) {
  const int v = threadIdx.x;  // 256 == V
  float s = 0.0f;
  for (int pb = 0; pb < pblocks; ++pb) s += partial[(size_t)pb * V + v];
  out[1 + v] = __logf(s);
  if (v == 0) {
    float acc = 0.0f;
#pragma unroll 8
    for (int i = 0; i < N; ++i) acc += nll[i];
    out[0] = acc / (float)N;
  }
}

extern "C" void kernel_launch(void* const* d_in, const int* in_sizes, int n_in,
                              void* d_out, int out_size, void* d_ws, size_t ws_size,
                              hipStream_t stream) {
  const float* lp   = (const float*)d_in[0];  // [T,N,V] fp32
  const float* lpri = (const float*)d_in[1];  // [1,V]   fp32
  const int*   tgt  = (const int*)d_in[2];    // [N,S]
  const int*   ilen = (const int*)d_in[3];    // [N]
  const int*   tlen = (const int*)d_in[4];    // [N]
  const int V = in_sizes[1];
  const int N = in_sizes[3];
  const int S = in_sizes[2] / N;
  const int T = in_sizes[0] / (N * V);

  int pblocks = 200;  // 32 + 200 = 232 blocks, all co-resident
  size_t need = ((size_t)pblocks * V + 64) * sizeof(float);
  if (ws_size < need) {
    long avail = (long)(ws_size / sizeof(float)) - 64;
    pblocks = (int)(avail / V);
    if (pblocks < 1) pblocks = 1;
  }

  float* out = (float*)d_out;                   // [0]=loss, [1..V]=prior logsumexp
  float* partial = (float*)d_ws;                // [pblocks*V]
  float* nll = partial + (size_t)pblocks * V;   // [N]

  ctc_fused_kernel<<<N + pblocks, 256, 0, stream>>>(lp, lpri, tgt, ilen, tlen,
                                                    nll, partial, pblocks, T, N, V, S);
  finalize_kernel<<<1, 256, 0, stream>>>(partial, pblocks, nll, out, N, V);
}

// Round 6
// 350.318 us; speedup vs baseline: 1.8004x; 1.5229x over previous
//
#include <hip/hip_runtime.h>

#define PRIOR_SCALE 0.3f
#define NEGF (-1e30f)
#define LOG2E_F 1.4426950408889634f
#define LN2_F 0.6931471805599453f
#define K_SS 16   // time steps per superstep (one barrier per K_SS steps)

// Fused waitcnt+barrier: ONE asm block with "memory" clobber. s_barrier alone
// (IntrNoMem) is NOT a compiler memory fence -- LDS reads may hoist between a
// separate waitcnt asm and the barrier (the round-5 race). Fusing closes it.
#define PHASE_BARRIER() \
  asm volatile("s_waitcnt lgkmcnt(0)\n\ts_barrier" ::: "memory")

__device__ __forceinline__ float fexp2(float x) { return __builtin_amdgcn_exp2f(x); }
__device__ __forceinline__ float flog2(float x) { return __builtin_amdgcn_logf(x); }

// base-2 logsumexp
__device__ __forceinline__ float lse2b(float a, float b) {
  float m = fmaxf(a, b);
  float d = fminf(a, b) - m;
  return m + flog2(1.0f + fexp2(d));
}
// 3-term: max term's exp2 is exactly 1 -> 2 exp + 1 log
__device__ __forceinline__ float lse3b(float a, float b, float c) {
  float mx = fmaxf(fmaxf(a, b), c);                      // v_max3
  float mn = fminf(fminf(a, b), c);                      // v_min3
  float md = fmaxf(fminf(a, b), fminf(fmaxf(a, b), c));  // v_med3
  return mx + flog2(1.0f + fexp2(md - mx) + fexp2(mn - mx));
}

// lane-1 -> lane shift via DPP wave_shr:1 (pure VALU, no LDS pipe).
// Lane 0 receives `fill` (invalid-lane rule returns `old` when bound_ctrl=0).
__device__ __forceinline__ float shr1_dpp(float x, float fill) {
  return __int_as_float(__builtin_amdgcn_update_dpp(
      __float_as_int(fill), __float_as_int(x), 0x138 /*wave_shr:1*/, 0xF, 0xF, false));
}

// Un-sinkable prefetch: global_load_dword (sgpr base + 32-bit voffset) with
// asm-pinned VGPR destinations. Compiler cannot sink/remat/spill these.
__device__ __forceinline__ void issue_pair(float& e, float& b, uint32_t offE,
                                           uint32_t offB, uint64_t base) {
  asm volatile("global_load_dword %0, %2, %4\n\t"
               "global_load_dword %1, %3, %4"
               : "=v"(e), "=v"(b)
               : "v"(offE), "v"(offB), "s"(base));
}
// Counted wait tied to the consumed values via data dependency (rule #18):
// the consumer reads the asm outputs, so it cannot be hoisted above the wait.
__device__ __forceinline__ void wait_pair(float& e, float& b) {
  asm volatile("s_waitcnt vmcnt(30)" : "+v"(e), "+v"(b));
}

// Blocks [0,N): CTC forward, 4 time-skewed waves (wave w runs superstep i in
// phase p=i+w; boundary alpha passes through once-written LDS mailbox mb[w][t],
// bulk-read per superstep). Blocks [N,N+pblocks): label-prior partial sums.
extern "C" __global__ void __launch_bounds__(256, 1)
ctc_fused_kernel(const float* __restrict__ lp, const float* __restrict__ lpri,
                 const int* __restrict__ tgt, const int* __restrict__ ilen,
                 const int* __restrict__ tlen, float* __restrict__ nll,
                 float* __restrict__ partial, int pblocks,
                 int T, int N, int V, int S) {
  if ((int)blockIdx.x >= N) {
    const int pb = blockIdx.x - N;
    const int v = threadIdx.x;  // V == 256 == blockDim.x
    float s = 0.0f;
    for (int t = pb; t < T; t += pblocks) {
      const float* base = lp + (size_t)t * N * V + v;
      for (int nn = 0; nn < N; ++nn) {
        float x = base[(size_t)nn * V];
        s += (t < ilen[nn]) ? __expf(x) : 0.0f;
      }
    }
    partial[(size_t)pb * V + v] = s;
    return;
  }

  // ---------------- CTC forward path ------------------------------------
  const int n = blockIdx.x;
  const int g = threadIdx.x;   // owns positions 2g (blank), 2g+1 (label g)
  const int lane = g & 63;
  const int wid = __builtin_amdgcn_readfirstlane(threadIdx.x >> 6);
  __shared__ __align__(16) float mb[3][2048];  // mb[w][t] = alpha(t)[128w+127]
  __shared__ float afin[513];

  const int len = __builtin_amdgcn_readfirstlane(ilen[n]);
  const int tl = tlen[n];

  const int* trow = tgt + n * S;
  const int tv = trow[g];
  const int tvp = (g > 0) ? trow[g - 1] : -1;
  const float sk = (g > 0 && tv != tvp) ? 0.0f : NEGF;
  const float ep1 = (-PRIOR_SCALE * lpri[tv]) * LOG2E_F;
  const float epb = (-PRIOR_SCALE * lpri[0]) * LOG2E_F;

  const float* rp = lp + (size_t)n * V;       // column 0 (blank) of batch n
  const uint32_t RBu = (uint32_t)(N * V * 4); // row stride in bytes (32 KB)
  const uint32_t tvb = (uint32_t)tv * 4u;
  const uint64_t gbase = (uint64_t)(uintptr_t)rp;

  // alpha init (t=0), base-2 domain (compiler loads; before any asm loads)
  float x0 = NEGF, x1 = NEGF, x2 = NEGF;
  {
    float b0 = rp[0], e0 = rp[tv];
    if (g == 0) { x0 = fmaf(b0, LOG2E_F, epb); x1 = fmaf(e0, LOG2E_F, ep1); }
  }
  if (g < 3) mb[g][0] = NEGF;

  // ---- emission ring: 16 named (e,b) pairs, asm-pinned prefetch ----
  float eR0, eR1, eR2, eR3, eR4, eR5, eR6, eR7,
        eR8, eR9, eR10, eR11, eR12, eR13, eR14, eR15;
  float bR0, bR1, bR2, bR3, bR4, bR5, bR6, bR7,
        bR8, bR9, bR10, bR11, bR12, bR13, bR14, bR15;
#define PRO(K) { uint32_t tt = (uint32_t)((1 + K < len) ? (1 + K) : (len - 1)); \
                 issue_pair(eR##K, bR##K, tt * RBu + tvb, tt * RBu, gbase); }
  PRO(0) PRO(1) PRO(2) PRO(3) PRO(4) PRO(5) PRO(6) PRO(7)
  PRO(8) PRO(9) PRO(10) PRO(11) PRO(12) PRO(13) PRO(14) PRO(15)
#undef PRO
  uint32_t ofB;   // byte offset of next refill row
  { uint32_t tn = (uint32_t)((1 + K_SS < len) ? (1 + K_SS) : (len - 1));
    ofB = tn * RBu; }

  float mv0, mv1, mv2, mv3, mv4, mv5, mv6, mv7,
        mv8, mv9, mv10, mv11, mv12, mv13, mv14, mv15;

  PHASE_BARRIER();  // mb[*][0] visible to all waves

  const int nss = (len - 1 + K_SS - 1) / K_SS;
  const int P = nss + 3;

#define STEP(KK, T_) {                                                         \
    const int t = (T_);                                                        \
    if (t < len) {                                                             \
      wait_pair(eR##KK, bR##KK);                                               \
      float eb = fmaf(bR##KK, LOG2E_F, epb);                                   \
      float e1 = fmaf(eR##KK, LOG2E_F, ep1);                                   \
      issue_pair(eR##KK, bR##KK, ofB + tvb, ofB, gbase);                       \
      ofB += ((t + 1 + K_SS) < len) ? RBu : 0u;                                \
      float am1 = shr1_dpp(x1, mv##KK);                                        \
      float x1o = x1;                                                          \
      float y0 = lse2b(x0, am1) + eb;                                          \
      float y1 = lse3b(x1, x0, am1 + sk) + e1;                                 \
      x0 = y0; x1 = y1;                                                        \
      if (g == 255) x2 = lse2b(x2, x1o) + eb;                                  \
      if (lane == 63 && wid < 3) mb[wid][t] = x1;                              \
    } }

  for (int p = 0; p < P; ++p) {
    const int i = p - wid;
    if (i >= 0 && i < nss) {
      const int t0 = 1 + i * K_SS;
      if (wid > 0) {
        // bulk mailbox read: mb[wid-1][t0-1 .. t0+14] (all >=1 phase old;
        // cannot hoist above PHASE_BARRIER's memory clobber)
        const float4* mrow = (const float4*)&mb[wid - 1][t0 - 1];  // 64B aligned
        float4 q0 = mrow[0], q1 = mrow[1], q2 = mrow[2], q3 = mrow[3];
        mv0 = q0.x; mv1 = q0.y; mv2 = q0.z; mv3 = q0.w;
        mv4 = q1.x; mv5 = q1.y; mv6 = q1.z; mv7 = q1.w;
        mv8 = q2.x; mv9 = q2.y; mv10 = q2.z; mv11 = q2.w;
        mv12 = q3.x; mv13 = q3.y; mv14 = q3.z; mv15 = q3.w;
      } else {
        mv0 = mv1 = mv2 = mv3 = mv4 = mv5 = mv6 = mv7 = NEGF;
        mv8 = mv9 = mv10 = mv11 = mv12 = mv13 = mv14 = mv15 = NEGF;
      }
      STEP(0, t0 + 0)  STEP(1, t0 + 1)  STEP(2, t0 + 2)  STEP(3, t0 + 3)
      STEP(4, t0 + 4)  STEP(5, t0 + 5)  STEP(6, t0 + 6)  STEP(7, t0 + 7)
      STEP(8, t0 + 8)  STEP(9, t0 + 9)  STEP(10, t0 + 10) STEP(11, t0 + 11)
      STEP(12, t0 + 12) STEP(13, t0 + 13) STEP(14, t0 + 14) STEP(15, t0 + 15)
    }
    PHASE_BARRIER();  // writes visible + waves realigned, single asm unit
  }
#undef STEP

  // drain outstanding asm loads, keep their dest regs live until drained
  asm volatile("s_waitcnt vmcnt(0)");
  asm volatile("" :: "v"(eR0), "v"(eR1), "v"(eR2), "v"(eR3), "v"(eR4),
                     "v"(eR5), "v"(eR6), "v"(eR7), "v"(eR8), "v"(eR9),
                     "v"(eR10), "v"(eR11), "v"(eR12), "v"(eR13), "v"(eR14), "v"(eR15));
  asm volatile("" :: "v"(bR0), "v"(bR1), "v"(bR2), "v"(bR3), "v"(bR4),
                     "v"(bR5), "v"(bR6), "v"(bR7), "v"(bR8), "v"(bR9),
                     "v"(bR10), "v"(bR11), "v"(bR12), "v"(bR13), "v"(bR14), "v"(bR15));

  afin[2 * g] = x0;
  afin[2 * g + 1] = x1;
  if (g == 255) afin[512] = x2;
  __syncthreads();
  if (g == 0) {
    const int i1 = 2 * tl;
    float ll = lse2b(afin[i1], afin[i1 - 1]) * LN2_F;
    nll[n] = -ll / (float)tl;
  }
}

extern "C" __global__ void finalize_kernel(const float* __restrict__ partial, int pblocks,
                                           const float* __restrict__ nll,
                                           float* __restrict__ out, int N, int V) {
  const int v = threadIdx.x;  // 256 == V
  float s = 0.0f;
  for (int pb = 0; pb < pblocks; ++pb) s += partial[(size_t)pb * V + v];
  out[1 + v] = __logf(s);
  if (v == 0) {
    float acc = 0.0f;
#pragma unroll 8
    for (int i = 0; i < N; ++i) acc += nll[i];
    out[0] = acc / (float)N;
  }
}

extern "C" void kernel_launch(void* const* d_in, const int* in_sizes, int n_in,
                              void* d_out, int out_size, void* d_ws, size_t ws_size,
                              hipStream_t stream) {
  const float* lp   = (const float*)d_in[0];  // [T,N,V] fp32
  const float* lpri = (const float*)d_in[1];  // [1,V]   fp32
  const int*   tgt  = (const int*)d_in[2];    // [N,S]
  const int*   ilen = (const int*)d_in[3];    // [N]
  const int*   tlen = (const int*)d_in[4];    // [N]
  const int V = in_sizes[1];
  const int N = in_sizes[3];
  const int S = in_sizes[2] / N;
  const int T = in_sizes[0] / (N * V);

  int pblocks = 200;  // 32 + 200 = 232 blocks, all co-resident
  size_t need = ((size_t)pblocks * V + 64) * sizeof(float);
  if (ws_size < need) {
    long avail = (long)(ws_size / sizeof(float)) - 64;
    pblocks = (int)(avail / V);
    if (pblocks < 1) pblocks = 1;
  }

  float* out = (float*)d_out;                   // [0]=loss, [1..V]=prior logsumexp
  float* partial = (float*)d_ws;                // [pblocks*V]
  float* nll = partial + (size_t)pblocks * V;   // [N]

  ctc_fused_kernel<<<N + pblocks, 256, 0, stream>>>(lp, lpri, tgt, ilen, tlen,
                                                    nll, partial, pblocks, T, N, V, S);
  finalize_kernel<<<1, 256, 0, stream>>>(partial, pblocks, nll, out, N, V);
}